// Round 7
// baseline (117.336 us; speedup 1.0000x reference)
//
#include <hip/hip_runtime.h>
#include <hip/hip_fp16.h>
#include <math.h>

#define N_OCT   16
#define NPAIR   8
#define NS      32768
#define N_BE    512        // B*E = 8*64
#define TPB_A   256
#define NCHUNK  4          // blocks per row in pass A/B
#define CHUNK   (NS / NCHUNK)      // 8192 samples per block
#define SPT_A   (CHUNK / TPB_A)    // 32 samples per thread
#define STRIDE  TPB_A              // recurrence step = 256 samples

typedef float v2f __attribute__((ext_vector_type(2)));
typedef _Float16 h4 __attribute__((ext_vector_type(4)));

static __device__ __forceinline__ v2f fma2(v2f a, v2f b, v2f c) {
    return __builtin_elementwise_fma(a, b, c);
}

// d_ws layout (bytes), rewritten every launch (harness poisons with 0xAA):
//   [0,       65536)  r      double[8192]   per-(be,oct) revolutions/sample
//   [65536,   98304)  c2h    float[8192]    2cos(STRIDE*w) hi
//   [98304,  131072)  c2l    float[8192]    2cos(STRIDE*w) lo (double-float)
//   [131072, 163840)  amp    float[8192]    decay^(o+1) (0 past nyquist)
//   [163840, 165888)  maxu   uint[512]      per-row |max| as uint bits
//   [262144, 262144+32MiB) raw _Float16[512*32768]  unnormalized waveform
// Requires ws_size >= ~33 MB (fills show ~200 MB of ws — ample).
#define WS_R(ws)    ((double*)(ws))
#define WS_C2H(ws)  ((float*)((char*)(ws) + 65536))
#define WS_C2L(ws)  ((float*)((char*)(ws) + 98304))
#define WS_AMP(ws)  ((float*)((char*)(ws) + 131072))
#define WS_MAXU(ws) ((unsigned*)((char*)(ws) + 163840))
#define WS_RAW(ws)  ((_Float16*)((char*)(ws) + 262144))

// Per-(be,octave) block-uniform constants (hoisted: R4 showed the
// sigmoid/log/exp/cos_f64 chains cost ~6us when paid per-wave).
// Also zeroes the atomicMax slots: 0xAA poison as uint bits would win
// every atomicMax against real float bits.
__global__ __launch_bounds__(256)
void f0res_setup(const float* __restrict__ f0_in,
                 const float* __restrict__ dc_in,
                 const float* __restrict__ fs_in,
                 void* __restrict__ ws)
{
    const int idx = blockIdx.x * 256 + threadIdx.x;   // 8192 = 512 rows x 16 oct
    if (idx >= N_BE * N_OCT) return;
    const int be = idx >> 4, o = idx & 15;
    if (idx < N_BE) WS_MAXU(ws)[idx] = 0u;

    const float f0a = fabsf(f0_in[be]);
    const float dc  = dc_in[be];
    const float fs  = fs_in[be];

    const float MINF = (float)(20.0 / 11025.0);
    const float FRNG = (float)(3000.0 / 11025.0 - 20.0 / 11025.0);

    // double sigmoid (reference applies sigmoid twice), decay ladder
    const float s1    = 1.0f / (1.0f + __expf(-dc));
    const float dv    = 1.0f / (1.0f + __expf(-s1));
    const float decay = 0.01f + dv * 0.9801f;          // (1-0.01)*0.99
    const float logd  = __logf(decay + 1e-12f);
    const float f0r   = (MINF + f0a * FRNG) * 3.14159274101257324f;

    // sequential float cumsum, matching the reference's jnp.cumsum
    float cl = 0.f, cf = 0.f;
    for (int i = 0; i <= o; ++i) { cl += logd; cf += fs; }
    float ed  = __expf(cl);                            // decay^(o+1)
    float f0s = f0r * cf;                              // rad/sample, float32
    float a   = ed;
    if (!(f0s < 1.0f)) { a = 0.0f; f0s = 0.0f; }       // nyquist cutoff

    const double inv2pi = 0.15915494309189535;
    double r = (double)f0s * inv2pi;                   // revolutions/sample

    // c2 = 2*cos(STRIDE*w) as a double-float pair: 2^-48 effective frequency
    // error (single-float c2 is ill-conditioned when STRIDE*w mod 2pi ~ 0/pi)
    double drev = r * (double)STRIDE;
    drev -= floor(drev);
    double c2d = 2.0 * cos(drev * 6.283185307179586);
    float  ch  = (float)c2d;

    WS_R(ws)[idx]   = r;
    WS_C2H(ws)[idx] = ch;
    WS_C2L(ws)[idx] = (float)(c2d - (double)ch);
    WS_AMP(ws)[idx] = a;
}

// PASS A — streaming compute. 2048 blocks; block handles a quarter-row
// (be = blk>>2, chunk = blk&3), thread t owns samples chunk*8192 + k*256 + t.
// Chebyshev recurrence x_{n+1} = c2*x_n - x_{n-1} (step 256), amp folded in,
// octaves paired into float2 for v_pk_fma_f32. Raw fp16 streamed to d_ws
// (stores overlap compute — no barrier-then-burst like the fused R4 design),
// row max merged via device-scope atomicMax on uint bits (values >= 0).
// No big LDS -> residency is VGPR-bound (~85 VGPR -> ~6 blocks/CU = 24
// waves/CU vs R4's LDS-capped 16). launch_bounds 2nd arg = 1: only verified
// spill-free form (R1/R2/R3: tighter bounds -> 64-VGPR cap -> 44-165 MB
// scratch spill traffic).
__global__ __launch_bounds__(TPB_A, 1)
void f0res_passA(const void* __restrict__ ws)
{
    __shared__ float wmax[TPB_A / 64];

    const int be    = blockIdx.x >> 2;
    const int chunk = blockIdx.x & 3;
    const int t     = threadIdx.x;
    const int s0    = chunk * CHUNK + t;               // first owned sample

    const double* __restrict__ Rtab = WS_R(ws)   + be * N_OCT;
    const float*  __restrict__ CH   = WS_C2H(ws) + be * N_OCT;
    const float*  __restrict__ CLo  = WS_C2L(ws) + be * N_OCT;
    const float*  __restrict__ AMP  = WS_AMP(ws) + be * N_OCT;

    v2f xp[NPAIR], xc[NPAIR], c2h[NPAIR], c2l[NPAIR];

    #pragma unroll
    for (int o = 0; o < N_OCT; ++o) {
        const double r = Rtab[o];
        const float  a = AMP[o];

        double p0 = r * (double)(s0 + 1);              // phase, revolutions
        p0 -= floor(p0);
        double pm = r * (double)(s0 + 1 - STRIDE);     // one step back
        pm -= floor(pm);                               // ok for negatives
        float xcur  = a * __builtin_amdgcn_sinf((float)p0);  // amp folded in
        float xprev = a * __builtin_amdgcn_sinf((float)pm);

        const int j = o >> 1;
        if ((o & 1) == 0) {
            xc[j].x = xcur;   xp[j].x = xprev;
            c2h[j].x = CH[o]; c2l[j].x = CLo[o];
        } else {
            xc[j].y = xcur;   xp[j].y = xprev;
            c2h[j].y = CH[o]; c2l[j].y = CLo[o];
        }
    }

    _Float16* __restrict__ raw = WS_RAW(ws) + (size_t)be * NS + chunk * CHUNK;

    float lmax = 0.0f;
    #pragma unroll 4
    for (int k = 0; k < SPT_A; ++k) {
        v2f acc2 = (v2f)(0.0f);
        #pragma unroll
        for (int j = 0; j < NPAIR; ++j) {
            acc2 += xc[j];                              // amp pre-folded
            v2f xn = fma2(c2h[j], xc[j], fma2(c2l[j], xc[j], -xp[j]));
            xp[j] = xc[j];
            xc[j] = xn;
        }
        float acc = acc2.x + acc2.y;
        raw[k * TPB_A + t] = (_Float16)acc;            // 128B/wave, coalesced
        lmax = fmaxf(lmax, fabsf(acc));
    }

    #pragma unroll
    for (int off = 32; off > 0; off >>= 1)
        lmax = fmaxf(lmax, __shfl_down(lmax, off, 64));
    if ((t & 63) == 0) wmax[t >> 6] = lmax;
    __syncthreads();
    if (t == 0) {
        float bmax = wmax[0];
        #pragma unroll
        for (int w = 1; w < TPB_A / 64; ++w) bmax = fmaxf(bmax, wmax[w]);
        atomicMax(WS_MAXU(ws) + be, __float_as_uint(bmax));  // bits monotonic >=0
    }
}

// PASS B — normalize. Intermediate 32 MB fp16 sits in LLC (256 MB) from
// pass A -> effectively write-bound (64 MB fp32 out).
__global__ __launch_bounds__(TPB_A)
void f0res_passB(const void* __restrict__ ws,
                 float* __restrict__ out)
{
    const int be    = blockIdx.x >> 2;
    const int chunk = blockIdx.x & 3;
    const int t     = threadIdx.x;

    const float mx   = __uint_as_float(WS_MAXU(ws)[be]);   // uniform -> s_load
    const float norm = 1.0f / (mx + 1e-8f);

    const h4* __restrict__ raw4 =
        (const h4*)(WS_RAW(ws) + (size_t)be * NS + chunk * CHUNK);
    float4* __restrict__ out4 =
        (float4*)(out + (size_t)be * NS + chunk * CHUNK);

    #pragma unroll
    for (int j = 0; j < CHUNK / 4 / TPB_A; ++j) {      // 8 float4 stores/thread
        int i = j * TPB_A + t;
        h4 v = raw4[i];                                // 8B/lane LDS-free load
        float4 o;
        o.x = (float)v.x * norm; o.y = (float)v.y * norm;
        o.z = (float)v.z * norm; o.w = (float)v.w * norm;
        out4[i] = o;
    }
}

extern "C" void kernel_launch(void* const* d_in, const int* in_sizes, int n_in,
                              void* d_out, int out_size, void* d_ws, size_t ws_size,
                              hipStream_t stream) {
    const float* f0 = (const float*)d_in[0];
    const float* dc = (const float*)d_in[1];
    const float* fs = (const float*)d_in[3];   // d_in[2] is "unused"
    float* out = (float*)d_out;

    hipLaunchKernelGGL(f0res_setup, dim3((N_BE * N_OCT) / 256), dim3(256),
                       0, stream, f0, dc, fs, d_ws);
    hipLaunchKernelGGL(f0res_passA, dim3(N_BE * NCHUNK), dim3(TPB_A),
                       0, stream, d_ws);
    hipLaunchKernelGGL(f0res_passB, dim3(N_BE * NCHUNK), dim3(TPB_A),
                       0, stream, d_ws, out);
}

// Round 8
// 104.232 us; speedup vs baseline: 1.1257x; 1.1257x over previous
//
#include <hip/hip_runtime.h>
#include <math.h>

#define N_OCT 16
#define NPAIR 8
#define NS    32768
#define TPB   512
#define SPT   (NS / TPB)   // 64 samples per thread
#define N_BE  512          // B*E = 8*64

typedef float v2f __attribute__((ext_vector_type(2)));

static __device__ __forceinline__ v2f fma2(v2f a, v2f b, v2f c) {
    return __builtin_elementwise_fma(a, b, c);
}

// SINGLE-DISPATCH fused kernel. One block per (b,e) row, thread t owns
// samples s = k*TPB + t (stride-512, coalesced 256B/wave dword stores).
//
// Phase A (lanes t<16 only): octave t's block-uniform constants — sigmoid^2
// decay ladder, nyquist-cut frequency, and the Chebyshev coefficient
// c2 = 2cos(TPB*w) as a DOUBLE-FLOAT pair (2^-48 effective frequency error;
// single-float c2 is ill-conditioned when TPB*w mod 2pi ~ 0/pi). Published
// through 160B of LDS. R0-R3 paid ~6us computing all 16 chains per-THREAD;
// one chain in 16 lanes is ~0.2us, cheaper than R4's separate setup
// dispatch + graph gap.
//
// Pass 1: storeless Chebyshev recurrence x_{n+1}=c2*x_n - x_{n-1} (step 512,
// amp folded into the oscillator state, octaves paired into float2 for
// v_pk_fma_f32), tracking |max| only -> pure VALU, near-full issue.
// Reduce to row max, then RE-INIT the oscillators (32 v_sin_f32) and pass 2
// recomputes bit-identical samples, scales by 1/max, stores straight to
// global. No fp16/LDS staging round-trip, no barrier-then-burst epilogue
// (R4's structure wasted ~15us there).
//
// LAUNCH BOUNDS: (512,1) is the only verified spill-free form on this ROCm
// (R1/R2: tighter bounds -> 64-VGPR cap -> 44-165MB scratch spill traffic).
__global__ __launch_bounds__(TPB, 1)
void f0res_fused(const float* __restrict__ f0_in,
                 const float* __restrict__ dc_in,
                 const float* __restrict__ fs_in,
                 float* __restrict__ out)
{
    __shared__ double sh_r[N_OCT];                 // revolutions/sample
    __shared__ float  sh_c2h[N_OCT], sh_c2l[N_OCT], sh_amp[N_OCT];
    __shared__ float  wmax[TPB / 64];

    const int be = blockIdx.x;
    const int t  = threadIdx.x;

    // ---- Phase A: per-octave constants, one octave per lane (t < 16) ----
    if (t < N_OCT) {
        const int o = t;
        const float f0a = fabsf(f0_in[be]);
        const float dc  = dc_in[be];
        const float fs  = fs_in[be];

        const float MINF = (float)(20.0 / 11025.0);
        const float FRNG = (float)(3000.0 / 11025.0 - 20.0 / 11025.0);

        // double sigmoid (reference applies sigmoid twice), decay ladder
        const float s1    = 1.0f / (1.0f + __expf(-dc));
        const float dv    = 1.0f / (1.0f + __expf(-s1));
        const float decay = 0.01f + dv * 0.9801f;      // (1-0.01)*0.99
        const float logd  = __logf(decay + 1e-12f);
        const float f0r   = (MINF + f0a * FRNG) * 3.14159274101257324f;

        // sequential float cumsum, matching the reference's jnp.cumsum
        float cl = 0.f, cf = 0.f;
        for (int i = 0; i <= o; ++i) { cl += logd; cf += fs; }
        float ed  = __expf(cl);                        // decay^(o+1)
        float f0s = f0r * cf;                          // rad/sample, float32
        float a   = ed;
        if (!(f0s < 1.0f)) { a = 0.0f; f0s = 0.0f; }   // nyquist cutoff

        const double inv2pi = 0.15915494309189535;
        double r = (double)f0s * inv2pi;               // revolutions/sample

        double drev = r * (double)TPB;
        drev -= floor(drev);
        double c2d = 2.0 * cos(drev * 6.283185307179586);
        float  ch  = (float)c2d;

        sh_r[o]   = r;
        sh_c2h[o] = ch;
        sh_c2l[o] = (float)(c2d - (double)ch);
        sh_amp[o] = a;
    }
    __syncthreads();

    // ---- oscillator init (used twice: pass 1 and pass 2) ----
    v2f xp[NPAIR], xc[NPAIR], c2h[NPAIR], c2l[NPAIR];
    #pragma unroll
    for (int o = 0; o < N_OCT; ++o) {
        const int j = o >> 1;
        float ch = sh_c2h[o], clo = sh_c2l[o];
        if ((o & 1) == 0) { c2h[j].x = ch; c2l[j].x = clo; }
        else              { c2h[j].y = ch; c2l[j].y = clo; }
    }

    auto init_osc = [&]() {
        #pragma unroll
        for (int o = 0; o < N_OCT; ++o) {
            const double r = sh_r[o];
            const float  a = sh_amp[o];
            double p0 = r * (double)(t + 1);           // phase in revolutions
            p0 -= floor(p0);
            double pm = r * (double)(t + 1 - TPB);
            pm -= floor(pm);
            float xcur  = a * __builtin_amdgcn_sinf((float)p0);  // amp folded
            float xprev = a * __builtin_amdgcn_sinf((float)pm);
            const int j = o >> 1;
            if ((o & 1) == 0) { xc[j].x = xcur; xp[j].x = xprev; }
            else              { xc[j].y = xcur; xp[j].y = xprev; }
        }
    };

    // ---- Pass 1: storeless, track |max| only ----
    init_osc();
    float lmax = 0.0f;
    #pragma unroll 4
    for (int k = 0; k < SPT; ++k) {
        v2f acc2 = (v2f)(0.0f);
        #pragma unroll
        for (int j = 0; j < NPAIR; ++j) {
            acc2 += xc[j];                              // amp pre-folded
            v2f xn = fma2(c2h[j], xc[j], fma2(c2l[j], xc[j], -xp[j]));
            xp[j] = xc[j];
            xc[j] = xn;
        }
        lmax = fmaxf(lmax, fabsf(acc2.x + acc2.y));
    }

    // block max reduction: wave shuffle then tiny LDS
    #pragma unroll
    for (int off = 32; off > 0; off >>= 1)
        lmax = fmaxf(lmax, __shfl_down(lmax, off, 64));
    if ((t & 63) == 0) wmax[t >> 6] = lmax;
    __syncthreads();
    float bmax = wmax[0];
    #pragma unroll
    for (int w = 1; w < TPB / 64; ++w) bmax = fmaxf(bmax, wmax[w]);
    const float norm = 1.0f / (bmax + 1e-8f);

    // ---- Pass 2: recompute (bit-identical to pass 1), scale, store ----
    init_osc();
    float* __restrict__ row = out + (size_t)be * NS;
    #pragma unroll 4
    for (int k = 0; k < SPT; ++k) {
        v2f acc2 = (v2f)(0.0f);
        #pragma unroll
        for (int j = 0; j < NPAIR; ++j) {
            acc2 += xc[j];
            v2f xn = fma2(c2h[j], xc[j], fma2(c2l[j], xc[j], -xp[j]));
            xp[j] = xc[j];
            xc[j] = xn;
        }
        row[k * TPB + t] = (acc2.x + acc2.y) * norm;   // 256B/wave, coalesced
    }
}

extern "C" void kernel_launch(void* const* d_in, const int* in_sizes, int n_in,
                              void* d_out, int out_size, void* d_ws, size_t ws_size,
                              hipStream_t stream) {
    const float* f0 = (const float*)d_in[0];
    const float* dc = (const float*)d_in[1];
    const float* fs = (const float*)d_in[3];   // d_in[2] is "unused"
    float* out = (float*)d_out;

    hipLaunchKernelGGL(f0res_fused, dim3(N_BE), dim3(TPB), 0, stream,
                       f0, dc, fs, out);
}